// Round 6
// baseline (794.340 us; speedup 1.0000x reference)
//
#include <hip/hip_runtime.h>
#include <stddef.h>
#include <math.h>

#define BS 8192
#define NNODE 25
#define TT 128
#define TCH 16                 // t-steps per staged LDS window
#define NW (TT / TCH)          // 8 windows
#define XPAD 65                // chain-dim stride: 65 = 64+1 -> bank spread
#define LOG2E 1.4426950408889634f

typedef float v2f __attribute__((ext_vector_type(2)));
typedef float v4f __attribute__((ext_vector_type(4)));

// Raw v_exp_f32 / v_rcp_f32. (__exp2f collides with glibc math.h macros.)
__device__ __forceinline__ float ex2(float x) { return __builtin_amdgcn_exp2f(x); }
__device__ __forceinline__ float rcp_(float x) { return __builtin_amdgcn_rcpf(x); }

// Polynomial exp2 on the FULL-RATE VALU pipe (no trans-pipe use).
// R6 experiment: the wall model that fits all prior rounds is per-CU
// trans-pipe throughput (4 waves x 7 trans x ~12cy ~= 336 cy/node ~= measured
// 331). Moving the 5 exps to FMA-pipe polynomials cuts trans ops 7 -> 2.
// n = rndne(x), f = x-n in [-0.5,0.5], deg-6 minimax (Cephes exp2f,
// rel err ~2e-7), scale via v_ldexp_f32 (exact, handles overflow/underflow).
__device__ __forceinline__ float ex2f(float x) {
  const float n = __builtin_rintf(x);     // v_rndne_f32
  const float f = x - n;                  // [-0.5, 0.5]
  const int ni = (int)n;                  // v_cvt_i32_f32
  float p = 1.535336188319500e-4f;
  p = fmaf(p, f, 1.339887440266574e-3f);
  p = fmaf(p, f, 9.618437357674640e-3f);
  p = fmaf(p, f, 5.550332471162809e-2f);
  p = fmaf(p, f, 2.402264791363012e-1f);
  p = fmaf(p, f, 6.931472028550421e-1f);
  p = fmaf(p, f, 1.0f);
  return ldexpf(p, ni);                   // v_ldexp_f32
}

// Static device buffers (no ws_size dependence). Fully rewritten every call.
__device__ float g_hf[NNODE * BS * 4];  // (i, b, d)
__device__ float g_hb[NNODE * BS * 4];

// Broadcast lane K of each quad (lanes 4q..4q+3) via DPP quad_perm — 1 VALU op.
template <int K>
__device__ __forceinline__ float bcast4(float v) {
  int s = __builtin_bit_cast(int, v);
  int r = __builtin_amdgcn_update_dpp(0, s, (K * 0x55), 0xF, 0xF, true);
  return __builtin_bit_cast(float, r);
}

// Packed gate accumulate: A(ig',fg') B(og',cc') += splat(s) * w.
__device__ __forceinline__ void acc2(v2f& A, v2f& B, float s, v2f wa, v2f wb) {
  v2f sv = {s, s};
  A = __builtin_elementwise_fma(sv, wa, A);
  B = __builtin_elementwise_fma(sv, wb, B);
}

// Full recurrence for one direction; DIR compile-time so staging index math
// and neighbor-row mapping are static. Block = 256 threads = 64 chains.
//
// Structure locked by R1/R3/R4: 4 lanes/chain, 1 wave/SIMD, row-split partial
// sums, pk_add tail. R6 change: ex2 -> ex2f (poly, VALU pipe) in the node
// update only. Gate math order unchanged; only the exp implementation
// differs (rel err ~2e-7 -> absmax ~1e-5, threshold 1.59e-2).
template <int DIR>
__device__ __forceinline__ void rnn_run(
    int tid, const float* __restrict__ xblk, float* __restrict__ xs,
    const float* __restrict__ h0, const float* __restrict__ c0,
    const float* __restrict__ Wx, const float* __restrict__ Wh,
    const float* __restrict__ Wn, const float* __restrict__ Bb,
    float* __restrict__ ho, int b) {
  const int d = tid & 3;
  const int bl = tid >> 2;  // local chain 0..63
  const int cI = d, cF = 4 + d, cO = 8 + d, cC = 12 + d;
  const float sS = -LOG2E, sC = 2.0f * LOG2E;

  // Packed prescaled weights. Input order k: 0=x, 1..4=h feats, 5..8=nb
  // [up,dn,lf,rt]. fwd rows [up,dn,lf,rt]=0,1,2,3; bwd order is [up,dn,rt,lf]
  // so lf-value uses row 3, rt-value row 2.
  v2f wA[9], wB[9];
  wA[0] = v2f{sS * Wx[cI], sS * Wx[cF]};
  wB[0] = v2f{sS * Wx[cO], sC * Wx[cC]};
#pragma unroll
  for (int k = 0; k < 4; ++k) {
    wA[1 + k] = v2f{sS * Wh[k * 16 + cI], sS * Wh[k * 16 + cF]};
    wB[1 + k] = v2f{sS * Wh[k * 16 + cO], sC * Wh[k * 16 + cC]};
  }
  const int nrow[4] = {0, 1, DIR ? 3 : 2, DIR ? 2 : 3};
#pragma unroll
  for (int k = 0; k < 4; ++k) {
    wA[5 + k] = v2f{sS * Wn[nrow[k] * 16 + cI], sS * Wn[nrow[k] * 16 + cF]};
    wB[5 + k] = v2f{sS * Wn[nrow[k] * 16 + cO], sC * Wn[nrow[k] * 16 + cC]};
  }
  const v2f bA = {sS * Bb[cI], sS * Bb[cF]};
  const v2f bB = {sS * Bb[cO], sC * Bb[cC]};

  float h[NNODE], c[NNODE], b3[NNODE];
#pragma unroll
  for (int i = 0; i < NNODE; ++i) {
    h[i] = h0[(i * BS + b) * 4 + d];
    c[i] = c0[(i * BS + b) * 4 + d];
    b3[i] = bcast4<3>(h[i]);
  }

  const int t4 = tid & 3;
  const int s0 = tid >> 2;

  for (int w = 0; w < NW; ++w) {
    __syncthreads();  // previous window's reads complete before overwrite
    // Stage window w: logical steps s=16w..16w+15 (bwd: t = 127-s).
    // Each thread: 25 float4 global loads (64B-aligned segments, every byte
    // consumed) -> 100 scalar LDS writes into xs[kk][i][bl] (stride XPAD).
#pragma unroll
    for (int r = 0; r < NNODE; ++r) {
      const int seg = s0 + 64 * r;       // 0..1599
      const int sbl = seg / 25;          // chain
      const int sii = seg - sbl * 25;    // node
      const int tb = (DIR ? (TT - TCH - TCH * w) : (TCH * w)) + 4 * t4;
      const v4f v = *(const v4f*)(xblk + ((size_t)sbl * NNODE + sii) * TT + tb);
#pragma unroll
      for (int j = 0; j < 4; ++j) {
        const int kk = DIR ? (15 - 4 * t4 - j) : (4 * t4 + j);
        xs[(kk * NNODE + sii) * XPAD + sbl] = v[j];
      }
    }
    __syncthreads();

#pragma unroll 1  // keep I$ small: body is the unrolled 25-node step
    for (int kk = 0; kk < TCH; ++kk) {
      // Batch the 25 x reads (quad-broadcast, conflict-free across quads).
      float xq[NNODE];
#pragma unroll
      for (int i = 0; i < NNODE; ++i) xq[i] = xs[(kk * NNODE + i) * XPAD + bl];

#pragma unroll
      for (int r = 0; r < 5; ++r) {
        // Phase A: partial gate sums for the whole row — every term except
        // lf. up (b3[i-5]) is same-t but row r-1 is already finished; dn/rt/
        // self/h-feats are prev-t. All 5 nodes independent.
        v2f PA[5], PB[5];
#pragma unroll
        for (int j = 0; j < 5; ++j) {
          const int i = r * 5 + j;
          const float f0 = bcast4<0>(h[i]);
          const float f1 = bcast4<1>(h[i]);
          const float f2 = bcast4<2>(h[i]);
          v2f A = bA, B = bB;
          acc2(A, B, xq[i], wA[0], wB[0]);
          acc2(A, B, f0, wA[1], wB[1]);
          acc2(A, B, f1, wA[2], wB[2]);
          acc2(A, B, f2, wA[3], wB[3]);
          acc2(A, B, b3[i], wA[4], wB[4]);
          if (i >= 5) acc2(A, B, b3[i - 5], wA[5], wB[5]);  // up (this t)
          if (i < 20) acc2(A, B, b3[i + 5], wA[6], wB[6]);  // dn (prev t)
          if (i < 24) acc2(A, B, b3[i + 1], wA[8], wB[8]);  // rt (prev t)
          PA[j] = A;
          PB[j] = B;
        }

        // Phase B: serial sweep — single lf FMA is the only same-t link.
#pragma unroll
        for (int j = 0; j < 5; ++j) {
          const int i = r * 5 + j;
          v2f A = PA[j], B = PB[j];
          if (i >= 1) acc2(A, B, b3[i - 1], wA[7], wB[7]);  // lf (serial dep)

          // A = (-log2e*ig, -log2e*fg), B = (-log2e*og, 2log2e*cc)
          const float Ei = ex2f(A.x);  // e^-ig
          const float Ef = ex2f(A.y);  // e^-fg
          const float Eo = ex2f(B.x);  // e^-og
          const float Ec = ex2f(B.y);  // e^{2cc}
          // Packed +1/-1 adds (3 pk_add replace 6 scalar adds):
          const v2f Dif = v2f{Ei, Ef} + v2f{1.0f, 1.0f};   // (1+Ei, 1+Ef)
          const v2f Ecpm = v2f{Ec, Ec} + v2f{1.0f, -1.0f}; // (Ec+1, Ec-1)
          // nc = c/(1+Ef) + (Ec-1)/((1+Ei)(Ec+1)), single rcp:
          const float P = Dif.x * Ecpm.x;
          const float num = fmaf(c[i], P, Ecpm.y * Dif.y);
          const float nc = num * rcp_(Dif.y * P);
          // h = sigmoid(og)*tanh(nc) = (1-En)/((1+En)(1+Eo)), single rcp:
          const float En = ex2f(-2.0f * LOG2E * nc);
          const v2f Uno = v2f{En, Eo} + v2f{1.0f, 1.0f};   // (1+En, 1+Eo)
          const float hn = (1.0f - En) * rcp_(Uno.x * Uno.y);
          c[i] = nc;
          h[i] = hn;
          b3[i] = bcast4<3>(hn);
        }
      }
    }
  }

#pragma unroll
  for (int i = 0; i < NNODE; ++i) ho[(i * BS + b) * 4 + d] = h[i];
}

// Quad scheme: 4 lanes per (batch, dir) chain; lane d owns feature d and gate
// cols {d,4+d,8+d,12+d}. grid (128, 2) x block 256 -> 1024 waves = 1/SIMD,
// 256 blocks = 1 block/CU (LDS 104 KB caps it there anyway). R3 (spill-
// tainted but directionally) says don't raise waves/SIMD — keep 1/SIMD.
__global__ __launch_bounds__(256, 1) void rnn_kernel(
    const float* __restrict__ x,
    const float* __restrict__ h0f, const float* __restrict__ c0f,
    const float* __restrict__ h0b, const float* __restrict__ c0b,
    const float* __restrict__ Wxf, const float* __restrict__ Whf,
    const float* __restrict__ Wnf, const float* __restrict__ bf,
    const float* __restrict__ Wxb, const float* __restrict__ Whb,
    const float* __restrict__ Wnb, const float* __restrict__ bb_) {
  __shared__ float xs[TCH * NNODE * XPAD];  // 104,000 B
  const int tid = threadIdx.x;
  const int b = blockIdx.x * 64 + (tid >> 2);
  const float* xblk = x + (size_t)(blockIdx.x * 64) * (NNODE * TT);
  if (blockIdx.y == 0) {
    rnn_run<0>(tid, xblk, xs, h0f, c0f, Wxf, Whf, Wnf, bf, g_hf, b);
  } else {
    rnn_run<1>(tid, xblk, xs, h0b, c0b, Wxb, Whb, Wnb, bb_, g_hb, b);
  }
}

// H(b,200) -> sigmoid(H@Wff+bff) -> softmax(ff@Wout+bout).
// 256 blocks x 256 threads, 32 batches/block (R5 version, kept).
__global__ __launch_bounds__(256) void ff_kernel(
    const float* __restrict__ Wff, const float* __restrict__ bff,
    const float* __restrict__ Wout, const float* __restrict__ bout,
    float* __restrict__ out) {
  __shared__ float Hs[32][200];   // 25,600 B
  __shared__ float ffs[32][130];  // 16,640 B (pad 130 -> bank spread)
  const int tid = threadIdx.x;
  const int b0 = blockIdx.x * 32;

  // Stage H: idx -> (node i, dir, batch bb). Consecutive tid = consecutive
  // bb -> consecutive float4 addresses within one dir array.
  for (int idx = tid; idx < NNODE * 2 * 32; idx += 256) {
    const int i = idx >> 6;          // node 0..24
    const int r = idx & 63;
    const int dir = r >> 5;          // 0: fwd, 1: bwd
    const int bb = r & 31;           // batch within block
    const float* src = dir ? g_hb : g_hf;
    const v4f v = *(const v4f*)(src + ((size_t)(i * BS + b0 + bb)) * 4);
#pragma unroll
    for (int f = 0; f < 4; ++f) Hs[bb][i * 8 + dir * 4 + f] = v[f];
  }
  __syncthreads();

  // ff = sigmoid(H @ Wff + bff): thread (n = tid&127, half = tid>>7) owns
  // 16 batches' accumulator for column n.
  {
    const int n = tid & 127;
    const int half = tid >> 7;  // batches [half*16, half*16+16)
    float acc[16];
    const float bv = bff[n];
#pragma unroll
    for (int q = 0; q < 16; ++q) acc[q] = bv;
    for (int k = 0; k < 200; ++k) {
      const float w = Wff[k * 128 + n];
#pragma unroll
      for (int q = 0; q < 16; ++q)
        acc[q] = fmaf(Hs[half * 16 + q][k], w, acc[q]);
    }
#pragma unroll
    for (int q = 0; q < 16; ++q)
      ffs[half * 16 + q][n] = rcp_(1.0f + ex2(-LOG2E * acc[q]));
  }
  __syncthreads();

  // out = softmax(ff @ Wout + bout): 64 threads = 32 batches x 2 classes,
  // all within wave 0 -> shfl_xor(.,1) pairs (bb, j=0) with (bb, j=1).
  if (tid < 64) {
    const int bb = tid >> 1;
    const int j = tid & 1;
    float z = bout[j];
    for (int n = 0; n < 128; ++n)
      z = fmaf(ffs[bb][n], Wout[n * 2 + j], z);
    const float zp = __shfl_xor(z, 1);
    const float m = fmaxf(z, zp);
    const float e = ex2(LOG2E * (z - m));
    const float ep = ex2(LOG2E * (zp - m));
    const float s = rcp_(e + ep);
    out[(size_t)(b0 + bb) * 2 + j] = e * s;
  }
}

extern "C" void kernel_launch(void* const* d_in, const int* in_sizes, int n_in,
                              void* d_out, int out_size, void* d_ws, size_t ws_size,
                              hipStream_t stream) {
  (void)in_sizes; (void)n_in; (void)out_size; (void)d_ws; (void)ws_size;
  const float* x    = (const float*)d_in[0];
  const float* h0f  = (const float*)d_in[1];
  const float* c0f  = (const float*)d_in[2];
  const float* h0b  = (const float*)d_in[3];
  const float* c0b  = (const float*)d_in[4];
  const float* Wxf  = (const float*)d_in[5];
  const float* Whf  = (const float*)d_in[6];
  const float* Wnf  = (const float*)d_in[7];
  const float* bf   = (const float*)d_in[8];
  const float* Wxb  = (const float*)d_in[9];
  const float* Whb  = (const float*)d_in[10];
  const float* Wnb  = (const float*)d_in[11];
  const float* bb   = (const float*)d_in[12];
  const float* Wff  = (const float*)d_in[13];
  const float* bff  = (const float*)d_in[14];
  const float* Wout = (const float*)d_in[15];
  const float* bout = (const float*)d_in[16];
  float* out = (float*)d_out;

  rnn_kernel<<<dim3(128, 2), dim3(256), 0, stream>>>(
      x, h0f, c0f, h0b, c0b, Wxf, Whf, Wnf, bf, Wxb, Whb, Wnb, bb);
  ff_kernel<<<dim3(256), dim3(256), 0, stream>>>(Wff, bff, Wout, bout, out);
}

// Round 7
// 563.159 us; speedup vs baseline: 1.4105x; 1.4105x over previous
//
#include <hip/hip_runtime.h>
#include <stddef.h>

#define BS 8192
#define NNODE 25
#define TT 128
#define TCH 16                 // t-steps per staged LDS window
#define NW (TT / TCH)          // 8 windows
#define XPAD 65                // chain-dim stride: 65 = 64+1 -> bank spread
#define LOG2E 1.4426950408889634f

typedef float v2f __attribute__((ext_vector_type(2)));
typedef float v4f __attribute__((ext_vector_type(4)));

// Raw v_exp_f32 / v_rcp_f32. (__exp2f collides with glibc math.h macros.)
__device__ __forceinline__ float ex2(float x) { return __builtin_amdgcn_exp2f(x); }
__device__ __forceinline__ float rcp_(float x) { return __builtin_amdgcn_rcpf(x); }
// Scheduler fence (emits NO instruction; blocks compiler reordering across).
__device__ __forceinline__ void SB() { __builtin_amdgcn_sched_barrier(0); }

// Static device buffers (no ws_size dependence). Fully rewritten every call.
__device__ float g_hf[NNODE * BS * 4];  // (i, b, d)
__device__ float g_hb[NNODE * BS * 4];

// Broadcast lane K of each quad (lanes 4q..4q+3) via DPP quad_perm — 1 VALU op.
template <int K>
__device__ __forceinline__ float bcast4(float v) {
  int s = __builtin_bit_cast(int, v);
  int r = __builtin_amdgcn_update_dpp(0, s, (K * 0x55), 0xF, 0xF, true);
  return __builtin_bit_cast(float, r);
}

// Packed gate accumulate: A(ig',fg') B(og',cc') += splat(s) * w.
__device__ __forceinline__ void acc2(v2f& A, v2f& B, float s, v2f wa, v2f wb) {
  v2f sv = {s, s};
  A = __builtin_elementwise_fma(sv, wa, A);
  B = __builtin_elementwise_fma(sv, wb, B);
}

// All 9 gate terms (incl. lf — caller guarantees b3[i-1] is final for this t).
// i is compile-time after unroll -> guards fold statically.
__device__ __forceinline__ void gates(
    int i, float x, const float* __restrict__ h, const float* __restrict__ b3,
    const v2f* __restrict__ wA, const v2f* __restrict__ wB, v2f bA, v2f bB,
    v2f& A, v2f& B) {
  const float f0 = bcast4<0>(h[i]);
  const float f1 = bcast4<1>(h[i]);
  const float f2 = bcast4<2>(h[i]);
  A = bA; B = bB;
  acc2(A, B, x, wA[0], wB[0]);
  acc2(A, B, f0, wA[1], wB[1]);
  acc2(A, B, f1, wA[2], wB[2]);
  acc2(A, B, f2, wA[3], wB[3]);
  acc2(A, B, b3[i], wA[4], wB[4]);
  if (i >= 5) acc2(A, B, b3[i - 5], wA[5], wB[5]);  // up (this t)
  if (i < 20) acc2(A, B, b3[i + 5], wA[6], wB[6]);  // dn (prev t)
  if (i >= 1) acc2(A, B, b3[i - 1], wA[7], wB[7]);  // lf (this t, serial)
  if (i < 24) acc2(A, B, b3[i + 1], wA[8], wB[8]);  // rt (prev t)
}

// Straight-line single-node update (fill/drain path). Identical math to R5.
__device__ __forceinline__ void node_full(
    int i, float x, float* __restrict__ h, float* __restrict__ c,
    float* __restrict__ b3, const v2f* __restrict__ wA,
    const v2f* __restrict__ wB, v2f bA, v2f bB) {
  v2f A, B;
  gates(i, x, h, b3, wA, wB, bA, bB, A, B);
  const float Ei = ex2(A.x), Ef = ex2(A.y), Eo = ex2(B.x), Ec = ex2(B.y);
  const v2f Dif = v2f{Ei, Ef} + v2f{1.0f, 1.0f};
  const v2f Ecp = v2f{Ec, Ec} + v2f{1.0f, -1.0f};
  const float P = Dif.x * Ecp.x;
  const float num = fmaf(c[i], P, Ecp.y * Dif.y);
  const float nc = num * rcp_(Dif.y * P);
  const float En = ex2(-2.0f * LOG2E * nc);
  const v2f Uno = v2f{En, Eo} + v2f{1.0f, 1.0f};
  const float hn = (1.0f - En) * rcp_(Uno.x * Uno.y);
  c[i] = nc;
  h[i] = hn;
  b3[i] = bcast4<3>(hn);
}

// Full recurrence for one direction; DIR compile-time. 64 chains/block.
//
// R7: the steady inner loop runs TWO independent chains (X = step k0 node
// 6+m, Y = step k1 node m; skew 6 makes them dependence-free — proven
// bit-exact in R1) in a hand-pipelined 10-phase interleave. Each phase does
// one chain's VALU work and ISSUES its next transcendental; the partner
// phase's issue stream covers the ~60cy dependent-trans latency before the
// consume. sched_barrier(0) pins the alternation (in-order wave issue means
// the compiler's serialization, not latency itself, caused the R1 null).
template <int DIR>
__device__ __forceinline__ void rnn_run(
    int tid, const float* __restrict__ xblk, float* __restrict__ xs,
    const float* __restrict__ h0, const float* __restrict__ c0,
    const float* __restrict__ Wx, const float* __restrict__ Wh,
    const float* __restrict__ Wn, const float* __restrict__ Bb,
    float* __restrict__ ho, int b) {
  const int d = tid & 3;
  const int bl = tid >> 2;  // local chain 0..63
  const int cI = d, cF = 4 + d, cO = 8 + d, cC = 12 + d;
  const float sS = -LOG2E, sC = 2.0f * LOG2E;

  // Packed prescaled weights. Input order k: 0=x, 1..4=h feats, 5..8=nb
  // [up,dn,lf,rt]. fwd rows [up,dn,lf,rt]=0,1,2,3; bwd is [up,dn,rt,lf].
  v2f wA[9], wB[9];
  wA[0] = v2f{sS * Wx[cI], sS * Wx[cF]};
  wB[0] = v2f{sS * Wx[cO], sC * Wx[cC]};
#pragma unroll
  for (int k = 0; k < 4; ++k) {
    wA[1 + k] = v2f{sS * Wh[k * 16 + cI], sS * Wh[k * 16 + cF]};
    wB[1 + k] = v2f{sS * Wh[k * 16 + cO], sC * Wh[k * 16 + cC]};
  }
  const int nrow[4] = {0, 1, DIR ? 3 : 2, DIR ? 2 : 3};
#pragma unroll
  for (int k = 0; k < 4; ++k) {
    wA[5 + k] = v2f{sS * Wn[nrow[k] * 16 + cI], sS * Wn[nrow[k] * 16 + cF]};
    wB[5 + k] = v2f{sS * Wn[nrow[k] * 16 + cO], sC * Wn[nrow[k] * 16 + cC]};
  }
  const v2f bA = {sS * Bb[cI], sS * Bb[cF]};
  const v2f bB = {sS * Bb[cO], sC * Bb[cC]};

  float h[NNODE], c[NNODE], b3[NNODE];
#pragma unroll
  for (int i = 0; i < NNODE; ++i) {
    h[i] = h0[(i * BS + b) * 4 + d];
    c[i] = c0[(i * BS + b) * 4 + d];
    b3[i] = bcast4<3>(h[i]);
  }

  const int t4 = tid & 3;
  const int s0 = tid >> 2;

  for (int w = 0; w < NW; ++w) {
    __syncthreads();  // previous window's reads complete before overwrite
#pragma unroll
    for (int r = 0; r < NNODE; ++r) {
      const int seg = s0 + 64 * r;       // 0..1599
      const int sbl = seg / 25;          // chain
      const int sii = seg - sbl * 25;    // node
      const int tb = (DIR ? (TT - TCH - TCH * w) : (TCH * w)) + 4 * t4;
      const v4f v = *(const v4f*)(xblk + ((size_t)sbl * NNODE + sii) * TT + tb);
#pragma unroll
      for (int j = 0; j < 4; ++j) {
        const int kk = DIR ? (15 - 4 * t4 - j) : (4 * t4 + j);
        xs[(kk * NNODE + sii) * XPAD + sbl] = v[j];
      }
    }
    __syncthreads();

#pragma unroll 1  // body = one unrolled timestep-PAIR (I$ ~21KB < 32KB)
    for (int kp = 0; kp < TCH / 2; ++kp) {
      const int k0 = 2 * kp, k1 = 2 * kp + 1;
      float xq0[NNODE], xq1[NNODE];
#pragma unroll
      for (int i = 0; i < NNODE; ++i) {
        xq0[i] = xs[(k0 * NNODE + i) * XPAD + bl];
        xq1[i] = xs[(k1 * NNODE + i) * XPAD + bl];
      }

      // fill: step k0, nodes 0..5 (plain serial)
#pragma unroll
      for (int i = 0; i < 6; ++i)
        node_full(i, xq0[i], h, c, b3, wA, wB, bA, bB);

      // steady: 19 pairs, 10-phase pinned interleave
#pragma unroll
      for (int m = 0; m < 19; ++m) {
        const int iX = 6 + m;  // step k0
        const int iY = m;      // step k1
        // g1: X gates + issue exp4
        v2f XA, XB;
        gates(iX, xq0[iX], h, b3, wA, wB, bA, bB, XA, XB);
        const float Eix = ex2(XA.x), Efx = ex2(XA.y);
        const float Eox = ex2(XB.x), Ecx = ex2(XB.y);
        SB();
        // g2: Y gates + issue exp4 (covers X exp latency)
        v2f YA, YB;
        gates(iY, xq1[iY], h, b3, wA, wB, bA, bB, YA, YB);
        const float Eiy = ex2(YA.x), Efy = ex2(YA.y);
        const float Eoy = ex2(YB.x), Ecy = ex2(YB.y);
        SB();
        // g3: X consume exp4 -> issue rcp1
        const v2f DifX = v2f{Eix, Efx} + v2f{1.0f, 1.0f};
        const v2f EcpX = v2f{Ecx, Ecx} + v2f{1.0f, -1.0f};
        const float PX = DifX.x * EcpX.x;
        const float numX = fmaf(c[iX], PX, EcpX.y * DifX.y);
        const float r1X = rcp_(DifX.y * PX);
        SB();
        // g4: Y consume exp4 -> issue rcp1
        const v2f DifY = v2f{Eiy, Efy} + v2f{1.0f, 1.0f};
        const v2f EcpY = v2f{Ecy, Ecy} + v2f{1.0f, -1.0f};
        const float PY = DifY.x * EcpY.x;
        const float numY = fmaf(c[iY], PY, EcpY.y * DifY.y);
        const float r1Y = rcp_(DifY.y * PY);
        SB();
        // g5: X consume rcp1 -> nc, issue En exp
        const float ncX = numX * r1X;
        c[iX] = ncX;
        const float EnX = ex2(-2.0f * LOG2E * ncX);
        SB();
        // g6: Y consume rcp1 -> nc, issue En exp
        const float ncY = numY * r1Y;
        c[iY] = ncY;
        const float EnY = ex2(-2.0f * LOG2E * ncY);
        SB();
        // g7: X consume En -> issue rcp2
        const v2f UnoX = v2f{EnX, Eox} + v2f{1.0f, 1.0f};
        const float r2X = rcp_(UnoX.x * UnoX.y);
        SB();
        // g8: Y consume En -> issue rcp2
        const v2f UnoY = v2f{EnY, Eoy} + v2f{1.0f, 1.0f};
        const float r2Y = rcp_(UnoY.x * UnoY.y);
        SB();
        // g9/g10: finish both
        const float hnX = (1.0f - EnX) * r2X;
        h[iX] = hnX;
        b3[iX] = bcast4<3>(hnX);
        const float hnY = (1.0f - EnY) * r2Y;
        h[iY] = hnY;
        b3[iY] = bcast4<3>(hnY);
        SB();
      }

      // drain: step k1, nodes 19..24 (plain serial)
#pragma unroll
      for (int i = 19; i < 25; ++i)
        node_full(i, xq1[i], h, c, b3, wA, wB, bA, bB);
    }
  }

#pragma unroll
  for (int i = 0; i < NNODE; ++i) ho[(i * BS + b) * 4 + d] = h[i];
}

// 4 lanes per chain; grid (128, 2) x block 256 -> 1024 waves = 1/SIMD,
// 256 blocks = 1 block/CU. R3: >1 wave/SIMD scales wall with issue — keep 1.
__global__ __launch_bounds__(256, 1) void rnn_kernel(
    const float* __restrict__ x,
    const float* __restrict__ h0f, const float* __restrict__ c0f,
    const float* __restrict__ h0b, const float* __restrict__ c0b,
    const float* __restrict__ Wxf, const float* __restrict__ Whf,
    const float* __restrict__ Wnf, const float* __restrict__ bf,
    const float* __restrict__ Wxb, const float* __restrict__ Whb,
    const float* __restrict__ Wnb, const float* __restrict__ bb_) {
  __shared__ float xs[TCH * NNODE * XPAD];  // 104,000 B
  const int tid = threadIdx.x;
  const int b = blockIdx.x * 64 + (tid >> 2);
  const float* xblk = x + (size_t)(blockIdx.x * 64) * (NNODE * TT);
  if (blockIdx.y == 0) {
    rnn_run<0>(tid, xblk, xs, h0f, c0f, Wxf, Whf, Wnf, bf, g_hf, b);
  } else {
    rnn_run<1>(tid, xblk, xs, h0b, c0b, Wxb, Whb, Wnb, bb_, g_hb, b);
  }
}

// H(b,200) -> sigmoid(H@Wff+bff) -> softmax(ff@Wout+bout).
// 256 blocks x 256 threads, 32 batches/block (R5 version, kept).
__global__ __launch_bounds__(256) void ff_kernel(
    const float* __restrict__ Wff, const float* __restrict__ bff,
    const float* __restrict__ Wout, const float* __restrict__ bout,
    float* __restrict__ out) {
  __shared__ float Hs[32][200];   // 25,600 B
  __shared__ float ffs[32][130];  // 16,640 B (pad 130 -> bank spread)
  const int tid = threadIdx.x;
  const int b0 = blockIdx.x * 32;

  for (int idx = tid; idx < NNODE * 2 * 32; idx += 256) {
    const int i = idx >> 6;          // node 0..24
    const int r = idx & 63;
    const int dir = r >> 5;          // 0: fwd, 1: bwd
    const int bb = r & 31;           // batch within block
    const float* src = dir ? g_hb : g_hf;
    const v4f v = *(const v4f*)(src + ((size_t)(i * BS + b0 + bb)) * 4);
#pragma unroll
    for (int f = 0; f < 4; ++f) Hs[bb][i * 8 + dir * 4 + f] = v[f];
  }
  __syncthreads();

  {
    const int n = tid & 127;
    const int half = tid >> 7;  // batches [half*16, half*16+16)
    float acc[16];
    const float bv = bff[n];
#pragma unroll
    for (int q = 0; q < 16; ++q) acc[q] = bv;
    for (int k = 0; k < 200; ++k) {
      const float w = Wff[k * 128 + n];
#pragma unroll
      for (int q = 0; q < 16; ++q)
        acc[q] = fmaf(Hs[half * 16 + q][k], w, acc[q]);
    }
#pragma unroll
    for (int q = 0; q < 16; ++q)
      ffs[half * 16 + q][n] = rcp_(1.0f + ex2(-LOG2E * acc[q]));
  }
  __syncthreads();

  if (tid < 64) {
    const int bb = tid >> 1;
    const int j = tid & 1;
    float z = bout[j];
    for (int n = 0; n < 128; ++n)
      z = fmaf(ffs[bb][n], Wout[n * 2 + j], z);
    const float zp = __shfl_xor(z, 1);
    const float m = fmaxf(z, zp);
    const float e = ex2(LOG2E * (z - m));
    const float ep = ex2(LOG2E * (zp - m));
    const float s = rcp_(e + ep);
    out[(size_t)(b0 + bb) * 2 + j] = e * s;
  }
}

extern "C" void kernel_launch(void* const* d_in, const int* in_sizes, int n_in,
                              void* d_out, int out_size, void* d_ws, size_t ws_size,
                              hipStream_t stream) {
  (void)in_sizes; (void)n_in; (void)out_size; (void)d_ws; (void)ws_size;
  const float* x    = (const float*)d_in[0];
  const float* h0f  = (const float*)d_in[1];
  const float* c0f  = (const float*)d_in[2];
  const float* h0b  = (const float*)d_in[3];
  const float* c0b  = (const float*)d_in[4];
  const float* Wxf  = (const float*)d_in[5];
  const float* Whf  = (const float*)d_in[6];
  const float* Wnf  = (const float*)d_in[7];
  const float* bf   = (const float*)d_in[8];
  const float* Wxb  = (const float*)d_in[9];
  const float* Whb  = (const float*)d_in[10];
  const float* Wnb  = (const float*)d_in[11];
  const float* bb   = (const float*)d_in[12];
  const float* Wff  = (const float*)d_in[13];
  const float* bff  = (const float*)d_in[14];
  const float* Wout = (const float*)d_in[15];
  const float* bout = (const float*)d_in[16];
  float* out = (float*)d_out;

  rnn_kernel<<<dim3(128, 2), dim3(256), 0, stream>>>(
      x, h0f, c0f, h0b, c0b, Wxf, Whf, Wnf, bf, Wxb, Whb, Wnb, bb);
  ff_kernel<<<dim3(256), dim3(256), 0, stream>>>(Wff, bff, Wout, bout, out);
}